// Round 10
// baseline (601.443 us; speedup 1.0000x reference)
//
#include <hip/hip_runtime.h>
#include <hip/hip_bf16.h>
#include <math.h>

#define L_TAU_C 0.8f

typedef _Float16 half2_t __attribute__((ext_vector_type(2)));

union U32H2 { unsigned int u; half2_t h; };
__device__ __forceinline__ half2_t h2(unsigned int v) { U32H2 x; x.u = v; return x.h; }

__device__ __forceinline__ float sigmoidf_(float x) {
    return 1.0f / (1.0f + __expf(-x));
}

// ---------------------------------------------------------------------------
// Kernel 1: transpose x [128][4096][20] f32 -> xT [128][20][4096] f16.
// ---------------------------------------------------------------------------
__global__ __launch_bounds__(256) void k_transpose16(const float* __restrict__ x,
                                                     _Float16* __restrict__ xT) {
    int gp = blockIdx.x * 256 + threadIdx.x;      // 0..524287
    int b = gp >> 12, p = gp & 4095;
    const float4* src = reinterpret_cast<const float4*>(x + (size_t)gp * 20);
    float v[20];
#pragma unroll
    for (int k = 0; k < 5; ++k) {
        float4 q = src[k];
        v[4 * k + 0] = q.x; v[4 * k + 1] = q.y; v[4 * k + 2] = q.z; v[4 * k + 3] = q.w;
    }
    _Float16* dst = xT + (size_t)b * 20 * 4096 + p;
#pragma unroll
    for (int t = 0; t < 20; ++t) dst[(size_t)t * 4096] = (_Float16)v[t];
}

// ---------------------------------------------------------------------------
// Kernel 2: fused conv + SNU(s1,y1) + maxpool + partial FC dot.
// R9 structure (barrierless, no-LDS, 378/384 threads, thread = 1 pool row x
// 2 pool cols) with the load path rebuilt against the R9 post-mortem:
//  * per conv row, ONE 16B-aligned dwordx4 pair + 1 dword covers the whole
//    18-half window (base u32 = 2*pcg - 2*(pcg&1), always 16B-aligned);
//    window u32s selected by compile-time-indexed v_cndmask on parity
//    (s[i] = off ? w[i+2] : w[i]) -- no runtime-indexed local arrays.
//    ~28 L1 lines/xr/wave vs R9's ~40, and 33 vs 44 load instrs/thread/t.
//  * rolling 2-row register prefetch: row xr+2 is issued while row xr is
//    consumed -> ~2 rows of loads always in flight (R9's VGPR=32 build
//    had ~1 xr in flight -> L1-latency serialization).
//  * __launch_bounds__(384,5): cap VGPR <= ~102 so 3 blocks/CU (18 waves)
//    still fit the 512-VGPR/EU pool.
// Weights in SGPRs (readfirstlane); v_dot2_f32_f16 + v_alignbit datapath;
// per-wave partials straight to global (6 waves/block).
// ---------------------------------------------------------------------------
__device__ __forceinline__ void load_row16(const _Float16* rp, uint4& A,
                                           uint4& B, unsigned& E) {
    A = *reinterpret_cast<const uint4*>(rp);
    B = *reinterpret_cast<const uint4*>(rp + 8);
    E = *reinterpret_cast<const unsigned*>(rp + 16);
}

__device__ __forceinline__ unsigned packf20(const float* p) {
    U32H2 pk; pk.h = half2_t{(_Float16)p[0], (_Float16)p[20]}; return pk.u;
}

__device__ __forceinline__ void load_row32(const float* rp, uint4& A,
                                           uint4& B, unsigned& E) {
    A.x = packf20(rp);       A.y = packf20(rp + 40);
    A.z = packf20(rp + 80);  A.w = packf20(rp + 120);
    B.x = packf20(rp + 160); B.y = packf20(rp + 200);
    B.z = packf20(rp + 240); B.w = packf20(rp + 280);
    E   = packf20(rp + 320);
}

template<int XMODE>   // 1 = f16 transposed input, 0 = strided f32 fallback
__global__ __launch_bounds__(384, 5) void k_conv_snu(
    const float* __restrict__ x,      // [128][4096][20]
    const _Float16* __restrict__ xT,  // [128][20][4096]
    const float* __restrict__ Wc,     // [6][1][10][10]
    const float* __restrict__ bc,     // [6]
    const float* __restrict__ W2,     // [4374][2]
    float* __restrict__ partw)        // [20][128][6][6][2]
{
    const int tid = threadIdx.x;
    const int bi = blockIdx.x;
    const int xcd = bi & 7, slot = bi >> 3;
    const int b = (slot / 6) * 8 + xcd;   // all 6 ch of b on same XCD
    const int ch = slot % 6;

    const bool active = tid < 378;
    const int r = tid / 14;           // pool row 0..26
    const int pcg = tid % 14;         // pool col pair: pool cols 2pcg, 2pcg+1
    const int row0 = 2 * r;
    const int off = pcg & 1;          // window parity
    const int hb = 4 * pcg - 4 * off; // 16B-aligned half base of the window

    // ---- weights -> SGPRs (one-time, uniform) ----
    const float* wb = Wc + ch * 100;
    unsigned int wsg[50];
#pragma unroll
    for (int i = 0; i < 50; ++i) {
        U32H2 pk;
        pk.h = half2_t{(_Float16)wb[2 * i], (_Float16)wb[2 * i + 1]};
        wsg[i] = (unsigned int)__builtin_amdgcn_readfirstlane((int)pk.u);
    }

    float s1[2][4], y1[2][4];
#pragma unroll
    for (int i = 0; i < 2; ++i)
#pragma unroll
        for (int j = 0; j < 4; ++j) { s1[i][j] = 0.f; y1[i][j] = 0.f; }

    const float bch = bc[ch];

    // FC weights for this thread's 2 pool cols (pc = 2pcg+k; pc>=27 masked 0)
    float w2r[2][2];
    w2r[0][0] = 0.f; w2r[0][1] = 0.f; w2r[1][0] = 0.f; w2r[1][1] = 0.f;
    if (active) {
#pragma unroll
        for (int k = 0; k < 2; ++k) {
            int pc = 2 * pcg + k;
            if (pc < 27) {
                int f0 = ch * 729 + r * 27 + pc;
                w2r[k][0] = W2[(size_t)f0 * 2 + 0];
                w2r[k][1] = W2[(size_t)f0 * 2 + 1];
            }
        }
    }

    const _Float16* xb16 = xT + (size_t)b * 20 * 4096;
    const float* xb32 = x + (size_t)b * 4096 * 20;

    for (int t = 0; t < 20; ++t) {
        float p0 = 0.f, p1 = 0.f;
        if (active) {
            float c0[4] = {0.f, 0.f, 0.f, 0.f};
            float c1[4] = {0.f, 0.f, 0.f, 0.f};

            const _Float16* tb16 = xb16 + (size_t)t * 4096 + hb;
            const float* tb32 = xb32 + (size_t)hb * 20 + t;

            // rolling 2-row prefetch registers
            uint4 a0, b0, a1, b1; unsigned e0, e1;
            if (XMODE == 1) {
                load_row16(tb16 + (size_t)(row0 + 0) * 64, a0, b0, e0);
                load_row16(tb16 + (size_t)(row0 + 1) * 64, a1, b1, e1);
            } else {
                load_row32(tb32 + (size_t)(row0 + 0) * 64 * 20, a0, b0, e0);
                load_row32(tb32 + (size_t)(row0 + 1) * 64 * 20, a1, b1, e1);
            }

#pragma unroll
            for (int xr = 0; xr < 11; ++xr) {
                // consume slot (xr&1) -- copies are SSA renames
                uint4 A  = (xr & 1) ? a1 : a0;
                uint4 Bq = (xr & 1) ? b1 : b0;
                unsigned E = (xr & 1) ? e1 : e0;
                // prefetch row xr+2 into the freed slot
                if (xr + 2 <= 10) {
                    if (XMODE == 1) {
                        const _Float16* rp = tb16 + (size_t)(row0 + xr + 2) * 64;
                        if (xr & 1) load_row16(rp, a1, b1, e1);
                        else        load_row16(rp, a0, b0, e0);
                    } else {
                        const float* rp = tb32 + (size_t)(row0 + xr + 2) * 64 * 20;
                        if (xr & 1) load_row32(rp, a1, b1, e1);
                        else        load_row32(rp, a0, b0, e0);
                    }
                }

                unsigned w_[9] = {A.x, A.y, A.z, A.w, Bq.x, Bq.y, Bq.z, Bq.w, E};
                unsigned s[7];
#pragma unroll
                for (int i = 0; i < 7; ++i) s[i] = off ? w_[i + 2] : w_[i];
                unsigned ss[6];
#pragma unroll
                for (int i = 0; i < 6; ++i)
                    ss[i] = (s[i] >> 16) | (s[i + 1] << 16);   // v_alignbit

                if (xr <= 9) {
#pragma unroll
                    for (int m = 0; m < 5; ++m) {
                        half2_t w = h2(wsg[xr * 5 + m]);
                        c0[0] = __builtin_amdgcn_fdot2(h2(s[m]),      w, c0[0], false);
                        c0[1] = __builtin_amdgcn_fdot2(h2(ss[m]),     w, c0[1], false);
                        c0[2] = __builtin_amdgcn_fdot2(h2(s[m + 1]),  w, c0[2], false);
                        c0[3] = __builtin_amdgcn_fdot2(h2(ss[m + 1]), w, c0[3], false);
                    }
                }
                if (xr >= 1) {
#pragma unroll
                    for (int m = 0; m < 5; ++m) {
                        half2_t w = h2(wsg[(xr - 1) * 5 + m]);
                        c1[0] = __builtin_amdgcn_fdot2(h2(s[m]),      w, c1[0], false);
                        c1[1] = __builtin_amdgcn_fdot2(h2(ss[m]),     w, c1[1], false);
                        c1[2] = __builtin_amdgcn_fdot2(h2(s[m + 1]),  w, c1[2], false);
                        c1[3] = __builtin_amdgcn_fdot2(h2(ss[m + 1]), w, c1[3], false);
                    }
                }
            }
            // SNU: s = relu(c + 0.8*s*(1-y)); y = sigmoid(s + bc)
#pragma unroll
            for (int j = 0; j < 4; ++j) {
                float sa = fmaxf(c0[j] + L_TAU_C * s1[0][j] * (1.f - y1[0][j]), 0.f);
                float sb = fmaxf(c1[j] + L_TAU_C * s1[1][j] * (1.f - y1[1][j]), 0.f);
                s1[0][j] = sa; s1[1][j] = sb;
                y1[0][j] = sigmoidf_(sa + bch);
                y1[1][j] = sigmoidf_(sb + bch);
            }
            // maxpool 2x2 (2 pool outs) + partial FC dot
            float h0 = fmaxf(fmaxf(y1[0][0], y1[0][1]), fmaxf(y1[1][0], y1[1][1]));
            float h1 = fmaxf(fmaxf(y1[0][2], y1[0][3]), fmaxf(y1[1][2], y1[1][3]));
            p0 = h0 * w2r[0][0] + h1 * w2r[1][0];
            p1 = h0 * w2r[0][1] + h1 * w2r[1][1];
        }
        // wave reduce -> direct global store of per-wave partials
#pragma unroll
        for (int off2 = 32; off2 >= 1; off2 >>= 1) {
            p0 += __shfl_down(p0, off2);
            p1 += __shfl_down(p1, off2);
        }
        if ((tid & 63) == 0) {
            float2 val; val.x = p0; val.y = p1;
            *reinterpret_cast<float2*>(
                &partw[((((size_t)t * 128 + b) * 6 + ch) * 6 + (tid >> 6)) * 2]) = val;
        }
    }
}

// ---------------------------------------------------------------------------
// Kernel 3: s2/y2 recurrence, out_rec, m, loss, acc. One block, 128 threads.
// ---------------------------------------------------------------------------
__global__ __launch_bounds__(128) void k_final(const float* __restrict__ partw,
                                               const void* __restrict__ yraw,
                                               const float* __restrict__ b2,
                                               float* __restrict__ out) {
    __shared__ float red[4];
    const int b = threadIdx.x;  // 0..127

    // labels may be int64 (reference) or int32: detect.
    const int* yi = (const int*)yraw;
    bool i64 = true;
    for (int k = 0; k < 64; ++k) {
        if (yi[2 * k + 1] != 0) { i64 = false; break; }
    }
    int lbl = i64 ? (int)((const long long*)yraw)[b] : yi[b];

    float b20 = b2[0], b21 = b2[1];
    float s20 = 0.f, s21 = 0.f, y20 = 0.f, y21 = 0.f, m0 = 0.f, m1 = 0.f;
    float* orec = out + 257 + b * 42;
    orec[0] = 0.f; orec[1] = 0.f;
    for (int t = 0; t < 20; ++t) {
        const float4* pp = reinterpret_cast<const float4*>(
            partw + ((size_t)t * 128 + b) * 72);
        float sum0 = 0.f, sum1 = 0.f;
#pragma unroll
        for (int i = 0; i < 18; ++i) {
            float4 a = pp[i];
            sum0 += a.x + a.z;
            sum1 += a.y + a.w;
        }
        s20 = fmaxf(sum0 + L_TAU_C * s20 * (1.f - y20), 0.f);
        s21 = fmaxf(sum1 + L_TAU_C * s21 * (1.f - y21), 0.f);
        y20 = sigmoidf_(s20 + b20);
        y21 = sigmoidf_(s21 + b21);
        orec[(t + 1) * 2 + 0] = y20;
        orec[(t + 1) * 2 + 1] = y21;
        m0 += y20; m1 += y21;
    }
    m0 *= 0.05f; m1 *= 0.05f;
    out[1 + b * 2 + 0] = m0;
    out[1 + b * 2 + 1] = m1;

    float mx = fmaxf(m0, m1);
    float lse = mx + logf(expf(m0 - mx) + expf(m1 - mx));
    float lossc = -(((lbl != 0) ? m1 : m0) - lse);
    int pred = (m1 > m0) ? 1 : 0;
    float accc = (pred == lbl) ? 1.f : 0.f;
#pragma unroll
    for (int off = 32; off >= 1; off >>= 1) {
        lossc += __shfl_down(lossc, off);
        accc += __shfl_down(accc, off);
    }
    if ((b & 63) == 0) { red[(b >> 6) * 2] = lossc; red[(b >> 6) * 2 + 1] = accc; }
    __syncthreads();
    if (b == 0) {
        out[0] = (red[0] + red[2]) * (1.f / 128.f);
        out[5633] = (red[1] + red[3]) * (1.f / 128.f);
    }
}

extern "C" void kernel_launch(void* const* d_in, const int* in_sizes, int n_in,
                              void* d_out, int out_size, void* d_ws, size_t ws_size,
                              hipStream_t stream) {
    const float* x  = (const float*)d_in[0];
    const void*  y  = d_in[1];
    const float* Wc = (const float*)d_in[2];
    const float* bc = (const float*)d_in[3];
    const float* W2 = (const float*)d_in[4];
    const float* b2 = (const float*)d_in[5];
    float* out = (float*)d_out;

    const size_t xt_bytes = (size_t)128 * 20 * 4096 * 2;         // 20,971,520
    const size_t partw_bytes = (size_t)20 * 128 * 6 * 6 * 2 * 4; // 737,280
    const int use16 = (ws_size >= xt_bytes + partw_bytes) ? 1 : 0;

    _Float16* xT = (_Float16*)d_ws;
    float* partw = use16 ? (float*)((char*)d_ws + xt_bytes) : (float*)d_ws;

    if (use16) {
        k_transpose16<<<2048, 256, 0, stream>>>(x, xT);
        k_conv_snu<1><<<768, 384, 0, stream>>>(x, xT, Wc, bc, W2, partw);
    } else {
        k_conv_snu<0><<<768, 384, 0, stream>>>(x, (const _Float16*)d_ws, Wc, bc, W2, partw);
    }
    k_final<<<1, 128, 0, stream>>>(partw, y, b2, out);
}

// Round 11
// 155.961 us; speedup vs baseline: 3.8564x; 3.8564x over previous
//
#include <hip/hip_runtime.h>
#include <hip/hip_bf16.h>
#include <math.h>

#define L_TAU_C 0.8f

typedef _Float16 half2_t __attribute__((ext_vector_type(2)));

union U32H2 { unsigned int u; half2_t h; };
__device__ __forceinline__ half2_t h2(unsigned int v) { U32H2 x; x.u = v; return x.h; }

__device__ __forceinline__ float sigmoidf_(float x) {
    return 1.0f / (1.0f + __expf(-x));
}

// ---------------------------------------------------------------------------
// Kernel 1: transpose x [128][4096][20] f32 -> xT [128][20][4096] f16.
// ---------------------------------------------------------------------------
__global__ __launch_bounds__(256) void k_transpose16(const float* __restrict__ x,
                                                     _Float16* __restrict__ xT) {
    int gp = blockIdx.x * 256 + threadIdx.x;      // 0..524287
    int b = gp >> 12, p = gp & 4095;
    const float4* src = reinterpret_cast<const float4*>(x + (size_t)gp * 20);
    float v[20];
#pragma unroll
    for (int k = 0; k < 5; ++k) {
        float4 q = src[k];
        v[4 * k + 0] = q.x; v[4 * k + 1] = q.y; v[4 * k + 2] = q.z; v[4 * k + 3] = q.w;
    }
    _Float16* dst = xT + (size_t)b * 20 * 4096 + p;
#pragma unroll
    for (int t = 0; t < 20; ++t) dst[(size_t)t * 4096] = (_Float16)v[t];
}

// ---------------------------------------------------------------------------
// Staging helpers (PROVEN R5/R6). LDS per buffer: copy A (halfs as-is) and
// copy B (shifted left 2 halfs), each [64 rows][64 halfs], b64-unit XOR
// swizzle: physical_unit = unit ^ sw2, sw2 = ((R>>1)&7)<<1.
// ---------------------------------------------------------------------------
__device__ __forceinline__ void stageA_B(_Float16* bufA, _Float16* bufB,
                                         int e, uint4 pf) {
    int R = e >> 3, h = e & 7;
    int sw2 = ((R >> 1) & 7) << 1;
    int u2h = (2 * h) ^ sw2;                         // even
    *reinterpret_cast<uint4*>(&bufA[R * 64 + u2h * 4]) = pf;
    uint2 midv; midv.x = pf.y; midv.y = pf.z;
    *reinterpret_cast<uint2*>(&bufB[R * 64 + u2h * 4]) = midv;
    *reinterpret_cast<unsigned int*>(&bufB[R * 64 + (u2h + 1) * 4]) = pf.w;
    if (h > 0) {
        int um = (2 * h - 1) ^ sw2;
        *reinterpret_cast<unsigned int*>(&bufB[R * 64 + um * 4 + 2]) = pf.x;
    }
}

__device__ __forceinline__ void stage_scalar(_Float16* bufA, _Float16* bufB,
                                             const float* xb, int t, int tid) {
#pragma unroll
    for (int k = 0; k < 16; ++k) {
        int p = tid + k * 256;
        int R = p >> 6, c = p & 63;
        int sw2 = ((R >> 1) & 7) << 1;
        _Float16 v = (_Float16)xb[(size_t)p * 20 + t];
        bufA[R * 64 + (((c >> 2) ^ sw2) << 2) + (c & 3)] = v;
        if (c >= 2) {
            int q = c - 2;
            bufB[R * 64 + (((q >> 2) ^ sw2) << 2) + (q & 3)] = v;
        }
    }
}

// ---------------------------------------------------------------------------
// Kernel 2: fused conv + SNU(s1,y1) + maxpool + partial FC dot.
// = Round-6 kernel (141us, proven) with ONE change: conv weights moved from
// LDS broadcasts (50 ds_read/thread/t -- the largest LDS-pipe term) to
// SGPRs via readfirstlane (proven R7, no spill). fdot2 reads the SGPR
// operand directly. Everything else identical to R6.
// ---------------------------------------------------------------------------
template<int XMODE>   // 1 = f16 transposed input, 0 = strided fallback
__global__ __launch_bounds__(256, 3) void k_conv_snu(
    const float* __restrict__ x,      // [128][4096][20]
    const _Float16* __restrict__ xT,  // [128][20][4096]
    const float* __restrict__ Wc,     // [6][1][10][10]
    const float* __restrict__ bc,     // [6]
    const float* __restrict__ W2,     // [4374][2]
    float* __restrict__ partw)        // [20][128][6][4][2]
{
    __shared__ _Float16 xsh[2][2][64 * 64];   // 32 KB: [buf][copyA/B]

    const int tid = threadIdx.x;
    const int bi = blockIdx.x;
    const int xcd = bi & 7, slot = bi >> 3;
    const int b = (slot / 6) * 8 + xcd;   // all 6 ch of b on same XCD
    const int ch = slot % 6;

    // ---- weights -> SGPRs (one-time, uniform; proven R7) ----
    const float* wb = Wc + ch * 100;
    unsigned int wsg[50];
#pragma unroll
    for (int i = 0; i < 50; ++i) {
        U32H2 pk;
        pk.h = half2_t{(_Float16)wb[2 * i], (_Float16)wb[2 * i + 1]};
        wsg[i] = (unsigned int)__builtin_amdgcn_readfirstlane((int)pk.u);
    }

    const bool active = tid < 243;
    const int r = tid / 9;            // pool row 0..26
    const int cg = tid % 9;           // col group 0..8, 6 conv cols each
    const int row0 = 2 * r;
    const int codd = cg & 1;          // odd cg reads copy B (start 6cg-2)
    const int u0 = (6 * cg - 2 * codd) >> 2;

    float s1[2][6], y1[2][6];
#pragma unroll
    for (int i = 0; i < 2; ++i)
#pragma unroll
        for (int j = 0; j < 6; ++j) { s1[i][j] = 0.f; y1[i][j] = 0.f; }

    const float bch = bc[ch];

    float w2r[3][2];
#pragma unroll
    for (int pj = 0; pj < 3; ++pj) { w2r[pj][0] = 0.f; w2r[pj][1] = 0.f; }
    if (active) {
        int f0 = ch * 729 + r * 27 + cg * 3;
#pragma unroll
        for (int pj = 0; pj < 3; ++pj) {
            w2r[pj][0] = W2[(size_t)(f0 + pj) * 2 + 0];
            w2r[pj][1] = W2[(size_t)(f0 + pj) * 2 + 1];
        }
    }

    // ---- prologue: stage t=0 into buf0 ----
    const uint4* gsrc = reinterpret_cast<const uint4*>(xT + (size_t)b * 20 * 4096);
    if (XMODE == 1) {
#pragma unroll
        for (int k = 0; k < 2; ++k) {
            int e = tid + k * 256;
            uint4 pf = gsrc[e];
            stageA_B(&xsh[0][0][0], &xsh[0][1][0], e, pf);
        }
    } else {
        stage_scalar(&xsh[0][0][0], &xsh[0][1][0], x + (size_t)b * 4096 * 20, 0, tid);
    }
    __syncthreads();

    for (int t = 0; t < 20; ++t) {
        // issue next-tile global loads EARLY (hide under compute)
        uint4 pf0, pf1;
        if (XMODE == 1 && t < 19) {
            pf0 = gsrc[(t + 1) * 512 + tid];
            pf1 = gsrc[(t + 1) * 512 + tid + 256];
        }

        float p0 = 0.f, p1 = 0.f;
        if (active) {
            const _Float16* cur = &xsh[t & 1][codd][0];
            float c0[6], c1[6];
#pragma unroll
            for (int j = 0; j < 6; ++j) { c0[j] = 0.f; c1[j] = 0.f; }

#pragma unroll
            for (int xr = 0; xr < 11; ++xr) {
                const int R = row0 + xr;
                const int sw2 = ((R >> 1) & 7) << 1;
                const _Float16* rowp = cur + R * 64;
                unsigned int s[8];
#pragma unroll
                for (int q = 0; q < 4; ++q) {
                    uint2 v = *reinterpret_cast<const uint2*>(
                        rowp + (((u0 + q) ^ sw2) << 2));
                    s[2 * q] = v.x; s[2 * q + 1] = v.y;
                }
                unsigned int ss[7];
#pragma unroll
                for (int i = 0; i < 7; ++i)
                    ss[i] = (s[i] >> 16) | (s[i + 1] << 16);   // v_alignbit

                if (xr <= 9) {
#pragma unroll
                    for (int m = 0; m < 5; ++m) {
                        half2_t w = h2(wsg[xr * 5 + m]);
                        c0[0] = __builtin_amdgcn_fdot2(h2(s[m]),      w, c0[0], false);
                        c0[2] = __builtin_amdgcn_fdot2(h2(s[m + 1]),  w, c0[2], false);
                        c0[4] = __builtin_amdgcn_fdot2(h2(s[m + 2]),  w, c0[4], false);
                        c0[1] = __builtin_amdgcn_fdot2(h2(ss[m]),     w, c0[1], false);
                        c0[3] = __builtin_amdgcn_fdot2(h2(ss[m + 1]), w, c0[3], false);
                        c0[5] = __builtin_amdgcn_fdot2(h2(ss[m + 2]), w, c0[5], false);
                    }
                }
                if (xr >= 1) {
#pragma unroll
                    for (int m = 0; m < 5; ++m) {
                        half2_t w = h2(wsg[(xr - 1) * 5 + m]);
                        c1[0] = __builtin_amdgcn_fdot2(h2(s[m]),      w, c1[0], false);
                        c1[2] = __builtin_amdgcn_fdot2(h2(s[m + 1]),  w, c1[2], false);
                        c1[4] = __builtin_amdgcn_fdot2(h2(s[m + 2]),  w, c1[4], false);
                        c1[1] = __builtin_amdgcn_fdot2(h2(ss[m]),     w, c1[1], false);
                        c1[3] = __builtin_amdgcn_fdot2(h2(ss[m + 1]), w, c1[3], false);
                        c1[5] = __builtin_amdgcn_fdot2(h2(ss[m + 2]), w, c1[5], false);
                    }
                }
            }
            // SNU: s = relu(c + 0.8*s*(1-y)); y = sigmoid(s + bc)
#pragma unroll
            for (int j = 0; j < 6; ++j) {
                float sa = fmaxf(c0[j] + L_TAU_C * s1[0][j] * (1.f - y1[0][j]), 0.f);
                float sb = fmaxf(c1[j] + L_TAU_C * s1[1][j] * (1.f - y1[1][j]), 0.f);
                s1[0][j] = sa; s1[1][j] = sb;
                y1[0][j] = sigmoidf_(sa + bch);
                y1[1][j] = sigmoidf_(sb + bch);
            }
            // maxpool 2x2 + partial FC dot
#pragma unroll
            for (int pj = 0; pj < 3; ++pj) {
                float h = fmaxf(fmaxf(y1[0][2 * pj], y1[0][2 * pj + 1]),
                                fmaxf(y1[1][2 * pj], y1[1][2 * pj + 1]));
                p0 += h * w2r[pj][0];
                p1 += h * w2r[pj][1];
            }
        }
        // wave reduce + direct global store of per-wave partials
#pragma unroll
        for (int off = 32; off >= 1; off >>= 1) {
            p0 += __shfl_down(p0, off);
            p1 += __shfl_down(p1, off);
        }
        if ((tid & 63) == 0) {
            float2 val; val.x = p0; val.y = p1;
            *reinterpret_cast<float2*>(
                &partw[((((size_t)t * 128 + b) * 6 + ch) * 4 + (tid >> 6)) * 2]) = val;
        }
        // write next tile into the other buffer
        if (t < 19) {
            _Float16* nA = &xsh[(t + 1) & 1][0][0];
            _Float16* nB = &xsh[(t + 1) & 1][1][0];
            if (XMODE == 1) {
                stageA_B(nA, nB, tid, pf0);
                stageA_B(nA, nB, tid + 256, pf1);
            } else {
                stage_scalar(nA, nB, x + (size_t)b * 4096 * 20, t + 1, tid);
            }
        }
        __syncthreads();
    }
}

// ---------------------------------------------------------------------------
// Kernel 3: s2/y2 recurrence, out_rec, m, loss, acc. One block, 128 threads.
// ---------------------------------------------------------------------------
__global__ __launch_bounds__(128) void k_final(const float* __restrict__ partw,
                                               const void* __restrict__ yraw,
                                               const float* __restrict__ b2,
                                               float* __restrict__ out) {
    __shared__ float red[4];
    const int b = threadIdx.x;  // 0..127

    // labels may be int64 (reference) or int32: detect.
    const int* yi = (const int*)yraw;
    bool i64 = true;
    for (int k = 0; k < 64; ++k) {
        if (yi[2 * k + 1] != 0) { i64 = false; break; }
    }
    int lbl = i64 ? (int)((const long long*)yraw)[b] : yi[b];

    float b20 = b2[0], b21 = b2[1];
    float s20 = 0.f, s21 = 0.f, y20 = 0.f, y21 = 0.f, m0 = 0.f, m1 = 0.f;
    float* orec = out + 257 + b * 42;
    orec[0] = 0.f; orec[1] = 0.f;
    for (int t = 0; t < 20; ++t) {
        const float4* pp = reinterpret_cast<const float4*>(
            partw + ((size_t)t * 128 + b) * 48);
        float sum0 = 0.f, sum1 = 0.f;
#pragma unroll
        for (int i = 0; i < 12; ++i) {
            float4 a = pp[i];
            sum0 += a.x + a.z;
            sum1 += a.y + a.w;
        }
        s20 = fmaxf(sum0 + L_TAU_C * s20 * (1.f - y20), 0.f);
        s21 = fmaxf(sum1 + L_TAU_C * s21 * (1.f - y21), 0.f);
        y20 = sigmoidf_(s20 + b20);
        y21 = sigmoidf_(s21 + b21);
        orec[(t + 1) * 2 + 0] = y20;
        orec[(t + 1) * 2 + 1] = y21;
        m0 += y20; m1 += y21;
    }
    m0 *= 0.05f; m1 *= 0.05f;
    out[1 + b * 2 + 0] = m0;
    out[1 + b * 2 + 1] = m1;

    float mx = fmaxf(m0, m1);
    float lse = mx + logf(expf(m0 - mx) + expf(m1 - mx));
    float lossc = -(((lbl != 0) ? m1 : m0) - lse);
    int pred = (m1 > m0) ? 1 : 0;
    float accc = (pred == lbl) ? 1.f : 0.f;
#pragma unroll
    for (int off = 32; off >= 1; off >>= 1) {
        lossc += __shfl_down(lossc, off);
        accc += __shfl_down(accc, off);
    }
    if ((b & 63) == 0) { red[(b >> 6) * 2] = lossc; red[(b >> 6) * 2 + 1] = accc; }
    __syncthreads();
    if (b == 0) {
        out[0] = (red[0] + red[2]) * (1.f / 128.f);
        out[5633] = (red[1] + red[3]) * (1.f / 128.f);
    }
}

extern "C" void kernel_launch(void* const* d_in, const int* in_sizes, int n_in,
                              void* d_out, int out_size, void* d_ws, size_t ws_size,
                              hipStream_t stream) {
    const float* x  = (const float*)d_in[0];
    const void*  y  = d_in[1];
    const float* Wc = (const float*)d_in[2];
    const float* bc = (const float*)d_in[3];
    const float* W2 = (const float*)d_in[4];
    const float* b2 = (const float*)d_in[5];
    float* out = (float*)d_out;

    const size_t xt_bytes = (size_t)128 * 20 * 4096 * 2;        // 20,971,520
    const size_t partw_bytes = (size_t)20 * 128 * 6 * 4 * 2 * 4; // 491,520
    const int use16 = (ws_size >= xt_bytes + partw_bytes) ? 1 : 0;

    _Float16* xT = (_Float16*)d_ws;
    float* partw = use16 ? (float*)((char*)d_ws + xt_bytes) : (float*)d_ws;

    if (use16) {
        k_transpose16<<<2048, 256, 0, stream>>>(x, xT);
        k_conv_snu<1><<<768, 256, 0, stream>>>(x, xT, Wc, bc, W2, partw);
    } else {
        k_conv_snu<0><<<768, 256, 0, stream>>>(x, (const _Float16*)d_ws, Wc, bc, W2, partw);
    }
    k_final<<<1, 128, 0, stream>>>(partw, y, b2, out);
}